// Round 4
// baseline (513.331 us; speedup 1.0000x reference)
//
#include <hip/hip_runtime.h>
#include <math.h>

#define S 13824          // 24*24*24
#define RT 216           // tokens per region (6^3)
#define SCALE 0.08838834764831845f  // 128^-0.5

// ---------------- 1x1 conv (channel matmul): out[o][s] = sum_c w[o][c]*in[c][s] + b[o]
// 16-column tiles -> 864 blocks. 256 threads: sl=tid&15 (column), wv=tid>>4 (0..15),
// each wv covers 4 output channels per pass; pass covers 64 channels.
__global__ __launch_bounds__(256) void proj_kernel(
    const float* __restrict__ in, const float* __restrict__ w,
    const float* __restrict__ bias, float* __restrict__ outp, int OC) {
  __shared__ float xs[128][16];
  const int tid = threadIdx.x;
  const int sbase = blockIdx.x * 16;
  for (int i = tid; i < 128 * 16; i += 256)
    xs[i >> 4][i & 15] = in[(size_t)(i >> 4) * S + sbase + (i & 15)];
  __syncthreads();
  const int sl = tid & 15;
  const int wv = tid >> 4;
  const int ogN = OC >> 6;
  for (int og = 0; og < ogN; ++og) {
    const int o = og * 64 + wv * 4;
    const float4* w0 = (const float4*)(w + (size_t)o * 128);
    const float4* w1 = w0 + 32;
    const float4* w2 = w0 + 64;
    const float4* w3 = w0 + 96;
    float a0 = 0.f, a1 = 0.f, a2 = 0.f, a3 = 0.f;
#pragma unroll 8
    for (int c4 = 0; c4 < 32; ++c4) {
      float4 f0 = w0[c4], f1 = w1[c4], f2 = w2[c4], f3 = w3[c4];
      float x0 = xs[c4 * 4 + 0][sl], x1 = xs[c4 * 4 + 1][sl];
      float x2 = xs[c4 * 4 + 2][sl], x3 = xs[c4 * 4 + 3][sl];
      a0 += f0.x * x0 + f0.y * x1 + f0.z * x2 + f0.w * x3;
      a1 += f1.x * x0 + f1.y * x1 + f1.z * x2 + f1.w * x3;
      a2 += f2.x * x0 + f2.y * x1 + f2.z * x2 + f2.w * x3;
      a3 += f3.x * x0 + f3.y * x1 + f3.z * x2 + f3.w * x3;
    }
    size_t base = (size_t)o * S + sbase + sl;
    outp[base]         = a0 + bias[o + 0];
    outp[base + S]     = a1 + bias[o + 1];
    outp[base + 2 * S] = a2 + bias[o + 2];
    outp[base + 3 * S] = a3 + bias[o + 3];
  }
}

// ---------------- region means of q and k (deterministic shuffle-tree reduce)
__global__ __launch_bounds__(256) void rmean_kernel(
    const float* __restrict__ qk, float* __restrict__ qr, float* __restrict__ kr) {
  const int n = blockIdx.x;
  const int tid = threadIdx.x, lane = tid & 63, wv = tid >> 6;
  const int rh = (n >> 4) * 6, rw = ((n >> 2) & 3) * 6, rd = (n & 3) * 6;
  int soff[4];
#pragma unroll
  for (int i = 0; i < 4; ++i) {
    int vx = lane + i * 64;
    if (vx < RT) {
      int p = vx / 36, qq = (vx / 6) % 6, u = vx % 6;
      soff[i] = (rh + p) * 576 + (rw + qq) * 24 + (rd + u);
    } else soff[i] = -1;
  }
  for (int ci = 0; ci < 64; ++ci) {
    int ch = wv + ci * 4;  // 0..255
    const float* src = qk + (size_t)ch * S;
    float ssum = 0.f;
#pragma unroll
    for (int i = 0; i < 4; ++i)
      if (soff[i] >= 0) ssum += src[soff[i]];
    for (int off = 32; off > 0; off >>= 1)
      ssum += __shfl_xor(ssum, off);
    if (lane == 0) {
      if (ch < 128) qr[n * 128 + ch] = ssum * (1.f / 216.f);
      else          kr[n * 128 + (ch - 128)] = ssum * (1.f / 216.f);
    }
  }
}

// ---------------- routing: top-4 with low-index tie-break (matches lax.top_k)
__global__ __launch_bounds__(64) void route_kernel(
    const float* __restrict__ qr, const float* __restrict__ kr, int* __restrict__ idxb) {
  const int n = blockIdx.x;
  const int t = threadIdx.x;  // key region
  float acc = 0.f;
  for (int c = 0; c < 128; ++c) acc += qr[n * 128 + c] * kr[t * 128 + c];
  float val = acc;
  int id = t;
  for (int j = 0; j < 4; ++j) {
    float bv = val;
    int bi = id;
    for (int off = 32; off > 0; off >>= 1) {
      float ov = __shfl_xor(bv, off);
      int oi = __shfl_xor(bi, off);
      if (ov > bv || (ov == bv && oi < bi)) { bv = ov; bi = oi; }
    }
    if (t == 0) idxb[n * 4 + j] = bi;
    if (id == bi) val = -INFINITY;
  }
}

// ---------------- attention: one 512-thread block per (region n, head mh).
// Two 4-wave halves (h = tid>>8) each process 2 of the 4 top-k kv-regions with
// online softmax (8-key chunks for ILP), then flash-merge via LDS.
__global__ __launch_bounds__(512) void attn_kernel(
    const float* __restrict__ qkv, const int* __restrict__ idxb, float* __restrict__ go) {
  __shared__ __align__(16) float ks[2][RT][20];
  __shared__ __align__(16) float vs[2][RT][20];
  const float* q = qkv;
  const float* k = qkv + (size_t)128 * S;
  const float* v = qkv + (size_t)256 * S;
  const int n = blockIdx.x, mh = blockIdx.y;
  const int tid = threadIdx.x;
  const int h = tid >> 8;        // which half (0/1) -> kv regions {0,1} or {2,3}
  const int qi = tid & 255;      // query token within region
  const int rh = (n >> 4) * 6, rw = ((n >> 2) & 3) * 6, rd = (n & 3) * 6;
  const bool active = qi < RT;
  float ql[16];
  int sq = 0;
  if (active) {
    int p = qi / 36, qq = (qi / 6) % 6, u = qi % 6;
    sq = (rh + p) * 576 + (rw + qq) * 24 + (rd + u);
#pragma unroll
    for (int d = 0; d < 16; ++d)
      ql[d] = q[(size_t)(mh * 16 + d) * S + sq] * SCALE;
  }
  float m = -INFINITY, denom = 0.f;
  float o[16];
#pragma unroll
  for (int d = 0; d < 16; ++d) o[d] = 0.f;

  for (int j = 0; j < 2; ++j) {
    const int r = idxb[n * 4 + h * 2 + j];
    const int gh = (r >> 4) * 6, gw = ((r >> 2) & 3) * 6, gd = (r & 3) * 6;
    __syncthreads();
    for (int i = qi; i < RT * 16; i += 256) {
      int t = i % RT, d = i / RT;
      int p = t / 36, qq = (t / 6) % 6, u = t % 6;
      int s = (gh + p) * 576 + (gw + qq) * 24 + (gd + u);
      ks[h][t][d] = k[(size_t)(mh * 16 + d) * S + s];
      vs[h][t][d] = v[(size_t)(mh * 16 + d) * S + s];
    }
    __syncthreads();
    if (active) {
      for (int key0 = 0; key0 < RT; key0 += 8) {
        float dot[8];
#pragma unroll
        for (int kk = 0; kk < 8; ++kk) {
          const float4* kp = (const float4*)&ks[h][key0 + kk][0];
          float4 k0 = kp[0], k1 = kp[1], k2 = kp[2], k3 = kp[3];
          dot[kk] = ql[0] * k0.x + ql[1] * k0.y + ql[2] * k0.z + ql[3] * k0.w
                  + ql[4] * k1.x + ql[5] * k1.y + ql[6] * k1.z + ql[7] * k1.w
                  + ql[8] * k2.x + ql[9] * k2.y + ql[10] * k2.z + ql[11] * k2.w
                  + ql[12] * k3.x + ql[13] * k3.y + ql[14] * k3.z + ql[15] * k3.w;
        }
        float cmax = fmaxf(fmaxf(fmaxf(dot[0], dot[1]), fmaxf(dot[2], dot[3])),
                           fmaxf(fmaxf(dot[4], dot[5]), fmaxf(dot[6], dot[7])));
        float mnew = fmaxf(m, cmax);
        float sc = __expf(m - mnew);   // m=-inf first time -> 0, state is zero anyway
        m = mnew;
        denom *= sc;
#pragma unroll
        for (int d = 0; d < 16; ++d) o[d] *= sc;
        float p8[8];
#pragma unroll
        for (int kk = 0; kk < 8; ++kk) p8[kk] = __expf(dot[kk] - m);
#pragma unroll
        for (int kk = 0; kk < 8; ++kk) denom += p8[kk];
#pragma unroll
        for (int kk = 0; kk < 8; ++kk) {
          const float4* vp = (const float4*)&vs[h][key0 + kk][0];
          float4 v0 = vp[0], v1 = vp[1], v2 = vp[2], v3 = vp[3];
          float p = p8[kk];
          o[0] += p * v0.x;  o[1] += p * v0.y;  o[2] += p * v0.z;  o[3] += p * v0.w;
          o[4] += p * v1.x;  o[5] += p * v1.y;  o[6] += p * v1.z;  o[7] += p * v1.w;
          o[8] += p * v2.x;  o[9] += p * v2.y;  o[10] += p * v2.z; o[11] += p * v2.w;
          o[12] += p * v3.x; o[13] += p * v3.y; o[14] += p * v3.z; o[15] += p * v3.w;
        }
      }
    }
  }
  // flash-merge the two halves (reuse ks storage as scratch)
  __syncthreads();
  float* mb = (float*)ks;
  if (h == 1 && active) {
    mb[qi * 18 + 0] = m;
    mb[qi * 18 + 1] = denom;
#pragma unroll
    for (int d = 0; d < 16; ++d) mb[qi * 18 + 2 + d] = o[d];
  }
  __syncthreads();
  if (h == 0 && active) {
    float m1 = mb[qi * 18 + 0], d1 = mb[qi * 18 + 1];
    float M = fmaxf(m, m1);
    float s0 = __expf(m - M), s1 = __expf(m1 - M);
    float inv = 1.f / (denom * s0 + d1 * s1);
#pragma unroll
    for (int d = 0; d < 16; ++d)
      go[(size_t)(mh * 16 + d) * S + sq] = (o[d] * s0 + mb[qi * 18 + 2 + d] * s1) * inv;
  }
}

// ---------------- lepe: depthwise 3x3x3 conv on v, accumulated into go.
// block = (channel, h-half): stage 14 h-slices (with halo) in LDS, 27 outputs/thread.
__global__ __launch_bounds__(256) void lepe_kernel(
    const float* __restrict__ v, const float* __restrict__ wl,
    const float* __restrict__ bl, float* __restrict__ go) {
  __shared__ float vt[14][24][24];
  const int c = blockIdx.x >> 1;
  const int hf = blockIdx.x & 1;
  const int h0 = hf * 12;
  const int tid = threadIdx.x;
  const float* vp = v + (size_t)c * S;
  for (int i = tid; i < 14 * 576; i += 256) {
    int hh = h0 - 1 + (i / 576);
    ((float*)vt)[i] = (hh >= 0 && hh < 24) ? vp[hh * 576 + (i % 576)] : 0.f;
  }
  float wreg[27];
#pragma unroll
  for (int i = 0; i < 27; ++i) wreg[i] = wl[c * 27 + i];
  const float bc = bl[c];
  __syncthreads();
  for (int t = 0; t < 27; ++t) {
    int oi = t * 256 + tid;           // 0..6911
    int hl = oi / 576, w = (oi / 24) % 24, d = oi % 24;
    float acc = bc;
#pragma unroll
    for (int a = 0; a < 3; ++a) {
#pragma unroll
      for (int b = 0; b < 3; ++b) {
        int ww = w + b - 1;
        if (ww < 0 || ww >= 24) continue;
#pragma unroll
        for (int e = 0; e < 3; ++e) {
          int dd = d + e - 1;
          if (dd < 0 || dd >= 24) continue;
          acc += vt[hl + a][ww][dd] * wreg[a * 9 + b * 3 + e];
        }
      }
    }
    go[(size_t)c * S + (h0 + hl) * 576 + w * 24 + d] += acc;
  }
}

extern "C" void kernel_launch(void* const* d_in, const int* in_sizes, int n_in,
                              void* d_out, int out_size, void* d_ws, size_t ws_size,
                              hipStream_t stream) {
  const float* x      = (const float*)d_in[0];
  const float* w_qkv  = (const float*)d_in[1];
  const float* b_qkv  = (const float*)d_in[2];
  const float* w_lepe = (const float*)d_in[3];
  const float* b_lepe = (const float*)d_in[4];
  const float* w_out  = (const float*)d_in[5];
  const float* b_out  = (const float*)d_in[6];
  float* out = (float*)d_out;
  float* ws  = (float*)d_ws;

  float* qkv  = ws;                        // 384*13824
  float* go   = qkv + (size_t)384 * S;     // 128*13824
  float* qr   = go + (size_t)128 * S;      // 64*128
  float* kr   = qr + 8192;                 // 64*128
  int*   idxb = (int*)(kr + 8192);         // 64*4

  proj_kernel<<<864, 256, 0, stream>>>(x, w_qkv, b_qkv, qkv, 384);
  rmean_kernel<<<64, 256, 0, stream>>>(qkv, qr, kr);
  route_kernel<<<64, 64, 0, stream>>>(qr, kr, idxb);
  attn_kernel<<<dim3(64, 8), 512, 0, stream>>>(qkv, idxb, go);
  lepe_kernel<<<256, 256, 0, stream>>>(qkv + (size_t)256 * S, w_lepe, b_lepe, go);
  proj_kernel<<<864, 256, 0, stream>>>(go, w_out, b_out, out, 128);
}

// Round 6
// 496.727 us; speedup vs baseline: 1.0334x; 1.0334x over previous
//
#include <hip/hip_runtime.h>
#include <math.h>

#define S 13824          // 24*24*24
#define RT 216           // tokens per region (6^3)
#define SCALE 0.08838834764831845f  // 128^-0.5

// ---------------- 1x1 conv (channel matmul): out[o][s] = sum_c w[o][c]*in[c][s] + b[o]
__global__ __launch_bounds__(256) void proj_kernel(
    const float* __restrict__ in, const float* __restrict__ w,
    const float* __restrict__ bias, float* __restrict__ outp, int OC) {
  __shared__ float xs[128][16];
  const int tid = threadIdx.x;
  const int sbase = blockIdx.x * 16;
  for (int i = tid; i < 128 * 16; i += 256)
    xs[i >> 4][i & 15] = in[(size_t)(i >> 4) * S + sbase + (i & 15)];
  __syncthreads();
  const int sl = tid & 15;
  const int wv = tid >> 4;
  const int ogN = OC >> 6;
  for (int og = 0; og < ogN; ++og) {
    const int o = og * 64 + wv * 4;
    const float4* w0 = (const float4*)(w + (size_t)o * 128);
    const float4* w1 = w0 + 32;
    const float4* w2 = w0 + 64;
    const float4* w3 = w0 + 96;
    float a0 = 0.f, a1 = 0.f, a2 = 0.f, a3 = 0.f;
#pragma unroll 8
    for (int c4 = 0; c4 < 32; ++c4) {
      float4 f0 = w0[c4], f1 = w1[c4], f2 = w2[c4], f3 = w3[c4];
      float x0 = xs[c4 * 4 + 0][sl], x1 = xs[c4 * 4 + 1][sl];
      float x2 = xs[c4 * 4 + 2][sl], x3 = xs[c4 * 4 + 3][sl];
      a0 += f0.x * x0 + f0.y * x1 + f0.z * x2 + f0.w * x3;
      a1 += f1.x * x0 + f1.y * x1 + f1.z * x2 + f1.w * x3;
      a2 += f2.x * x0 + f2.y * x1 + f2.z * x2 + f2.w * x3;
      a3 += f3.x * x0 + f3.y * x1 + f3.z * x2 + f3.w * x3;
    }
    size_t base = (size_t)o * S + sbase + sl;
    outp[base]         = a0 + bias[o + 0];
    outp[base + S]     = a1 + bias[o + 1];
    outp[base + 2 * S] = a2 + bias[o + 2];
    outp[base + 3 * S] = a3 + bias[o + 3];
  }
}

// ---------------- region means of q and k (deterministic shuffle-tree reduce)
__global__ __launch_bounds__(256) void rmean_kernel(
    const float* __restrict__ qk, float* __restrict__ qr, float* __restrict__ kr) {
  const int n = blockIdx.x;
  const int tid = threadIdx.x, lane = tid & 63, wv = tid >> 6;
  const int rh = (n >> 4) * 6, rw = ((n >> 2) & 3) * 6, rd = (n & 3) * 6;
  int soff[4];
#pragma unroll
  for (int i = 0; i < 4; ++i) {
    int vx = lane + i * 64;
    if (vx < RT) {
      int p = vx / 36, qq = (vx / 6) % 6, u = vx % 6;
      soff[i] = (rh + p) * 576 + (rw + qq) * 24 + (rd + u);
    } else soff[i] = -1;
  }
  for (int ci = 0; ci < 64; ++ci) {
    int ch = wv + ci * 4;  // 0..255
    const float* src = qk + (size_t)ch * S;
    float ssum = 0.f;
#pragma unroll
    for (int i = 0; i < 4; ++i)
      if (soff[i] >= 0) ssum += src[soff[i]];
    for (int off = 32; off > 0; off >>= 1)
      ssum += __shfl_xor(ssum, off);
    if (lane == 0) {
      if (ch < 128) qr[n * 128 + ch] = ssum * (1.f / 216.f);
      else          kr[n * 128 + (ch - 128)] = ssum * (1.f / 216.f);
    }
  }
}

// ---------------- routing: top-4 with low-index tie-break (matches lax.top_k)
__global__ __launch_bounds__(64) void route_kernel(
    const float* __restrict__ qr, const float* __restrict__ kr, int* __restrict__ idxb) {
  const int n = blockIdx.x;
  const int t = threadIdx.x;  // key region
  float acc = 0.f;
  for (int c = 0; c < 128; ++c) acc += qr[n * 128 + c] * kr[t * 128 + c];
  float val = acc;
  int id = t;
  for (int j = 0; j < 4; ++j) {
    float bv = val;
    int bi = id;
    for (int off = 32; off > 0; off >>= 1) {
      float ov = __shfl_xor(bv, off);
      int oi = __shfl_xor(bi, off);
      if (ov > bv || (ov == bv && oi < bi)) { bv = ov; bi = oi; }
    }
    if (t == 0) idxb[n * 4 + j] = bi;
    if (id == bi) val = -INFINITY;
  }
}

// ---------------- attention: one 512-thread block per (region n, head mh).
// Two 4-wave halves (h = tid>>8) each process 2 of the 4 top-k kv-regions with
// online softmax (8-key chunks for ILP), then flash-merge via LDS.
// __launch_bounds__(512, 4): 4 waves/SIMD -> 2 blocks/CU, VGPR cap 128 (round-4's
// cap of 68 caused inner-loop spills: FETCH 78MB, WRITE 13.8MB, 200us).
__global__ __launch_bounds__(512, 4) void attn_kernel(
    const float* __restrict__ qkv, const int* __restrict__ idxb, float* __restrict__ go) {
  __shared__ __align__(16) float ks[2][RT][20];
  __shared__ __align__(16) float vs[2][RT][20];
  const float* q = qkv;
  const float* k = qkv + (size_t)128 * S;
  const float* v = qkv + (size_t)256 * S;
  const int n = blockIdx.x, mh = blockIdx.y;
  const int tid = threadIdx.x;
  const int h = tid >> 8;        // which half (0/1) -> kv regions {0,1} or {2,3}
  const int qi = tid & 255;      // query token within region
  const int rh = (n >> 4) * 6, rw = ((n >> 2) & 3) * 6, rd = (n & 3) * 6;
  const bool active = qi < RT;
  float ql[16];
  int sq = 0;
  if (active) {
    int p = qi / 36, qq = (qi / 6) % 6, u = qi % 6;
    sq = (rh + p) * 576 + (rw + qq) * 24 + (rd + u);
#pragma unroll
    for (int d = 0; d < 16; ++d)
      ql[d] = q[(size_t)(mh * 16 + d) * S + sq] * SCALE;
  }
  float m = -INFINITY, denom = 0.f;
  float o[16];
#pragma unroll
  for (int d = 0; d < 16; ++d) o[d] = 0.f;

  for (int j = 0; j < 2; ++j) {
    const int r = idxb[n * 4 + h * 2 + j];
    const int gh = (r >> 4) * 6, gw = ((r >> 2) & 3) * 6, gd = (r & 3) * 6;
    __syncthreads();
    for (int i = qi; i < RT * 16; i += 256) {
      int t = i % RT, d = i / RT;
      int p = t / 36, qq = (t / 6) % 6, u = t % 6;
      int s = (gh + p) * 576 + (gw + qq) * 24 + (gd + u);
      ks[h][t][d] = k[(size_t)(mh * 16 + d) * S + s];
      vs[h][t][d] = v[(size_t)(mh * 16 + d) * S + s];
    }
    __syncthreads();
    if (active) {
      for (int key0 = 0; key0 < RT; key0 += 8) {
        float dot[8];
#pragma unroll
        for (int kk = 0; kk < 8; ++kk) {
          const float4* kp = (const float4*)&ks[h][key0 + kk][0];
          float4 k0 = kp[0], k1 = kp[1], k2 = kp[2], k3 = kp[3];
          dot[kk] = ql[0] * k0.x + ql[1] * k0.y + ql[2] * k0.z + ql[3] * k0.w
                  + ql[4] * k1.x + ql[5] * k1.y + ql[6] * k1.z + ql[7] * k1.w
                  + ql[8] * k2.x + ql[9] * k2.y + ql[10] * k2.z + ql[11] * k2.w
                  + ql[12] * k3.x + ql[13] * k3.y + ql[14] * k3.z + ql[15] * k3.w;
        }
        float cmax = fmaxf(fmaxf(fmaxf(dot[0], dot[1]), fmaxf(dot[2], dot[3])),
                           fmaxf(fmaxf(dot[4], dot[5]), fmaxf(dot[6], dot[7])));
        float mnew = fmaxf(m, cmax);
        float sc = __expf(m - mnew);   // m=-inf first time -> 0, state is zero anyway
        m = mnew;
        denom *= sc;
#pragma unroll
        for (int d = 0; d < 16; ++d) o[d] *= sc;
        float p8[8];
#pragma unroll
        for (int kk = 0; kk < 8; ++kk) p8[kk] = __expf(dot[kk] - m);
#pragma unroll
        for (int kk = 0; kk < 8; ++kk) denom += p8[kk];
#pragma unroll
        for (int kk = 0; kk < 8; ++kk) {
          const float4* vp = (const float4*)&vs[h][key0 + kk][0];
          float4 v0 = vp[0], v1 = vp[1], v2 = vp[2], v3 = vp[3];
          float p = p8[kk];
          o[0] += p * v0.x;  o[1] += p * v0.y;  o[2] += p * v0.z;  o[3] += p * v0.w;
          o[4] += p * v1.x;  o[5] += p * v1.y;  o[6] += p * v1.z;  o[7] += p * v1.w;
          o[8] += p * v2.x;  o[9] += p * v2.y;  o[10] += p * v2.z; o[11] += p * v2.w;
          o[12] += p * v3.x; o[13] += p * v3.y; o[14] += p * v3.z; o[15] += p * v3.w;
        }
      }
    }
  }
  // flash-merge the two halves (reuse ks storage as scratch)
  __syncthreads();
  float* mb = (float*)ks;
  if (h == 1 && active) {
    mb[qi * 18 + 0] = m;
    mb[qi * 18 + 1] = denom;
#pragma unroll
    for (int d = 0; d < 16; ++d) mb[qi * 18 + 2 + d] = o[d];
  }
  __syncthreads();
  if (h == 0 && active) {
    float m1 = mb[qi * 18 + 0], d1 = mb[qi * 18 + 1];
    float M = fmaxf(m, m1);
    float s0 = __expf(m - M), s1 = __expf(m1 - M);
    float inv = 1.f / (denom * s0 + d1 * s1);
#pragma unroll
    for (int d = 0; d < 16; ++d)
      go[(size_t)(mh * 16 + d) * S + sq] = (o[d] * s0 + mb[qi * 18 + 2 + d] * s1) * inv;
  }
}

// ---------------- lepe: depthwise 3x3x3 conv on v, accumulated into go.
__global__ __launch_bounds__(256) void lepe_kernel(
    const float* __restrict__ v, const float* __restrict__ wl,
    const float* __restrict__ bl, float* __restrict__ go) {
  __shared__ float vt[14][24][24];
  const int c = blockIdx.x >> 1;
  const int hf = blockIdx.x & 1;
  const int h0 = hf * 12;
  const int tid = threadIdx.x;
  const float* vp = v + (size_t)c * S;
  for (int i = tid; i < 14 * 576; i += 256) {
    int hh = h0 - 1 + (i / 576);
    ((float*)vt)[i] = (hh >= 0 && hh < 24) ? vp[hh * 576 + (i % 576)] : 0.f;
  }
  float wreg[27];
#pragma unroll
  for (int i = 0; i < 27; ++i) wreg[i] = wl[c * 27 + i];
  const float bc = bl[c];
  __syncthreads();
  for (int t = 0; t < 27; ++t) {
    int oi = t * 256 + tid;           // 0..6911
    int hl = oi / 576, w = (oi / 24) % 24, d = oi % 24;
    float acc = bc;
#pragma unroll
    for (int a = 0; a < 3; ++a) {
#pragma unroll
      for (int b = 0; b < 3; ++b) {
        int ww = w + b - 1;
        if (ww < 0 || ww >= 24) continue;
#pragma unroll
        for (int e = 0; e < 3; ++e) {
          int dd = d + e - 1;
          if (dd < 0 || dd >= 24) continue;
          acc += vt[hl + a][ww][dd] * wreg[a * 9 + b * 3 + e];
        }
      }
    }
    go[(size_t)c * S + (h0 + hl) * 576 + w * 24 + d] += acc;
  }
}

extern "C" void kernel_launch(void* const* d_in, const int* in_sizes, int n_in,
                              void* d_out, int out_size, void* d_ws, size_t ws_size,
                              hipStream_t stream) {
  const float* x      = (const float*)d_in[0];
  const float* w_qkv  = (const float*)d_in[1];
  const float* b_qkv  = (const float*)d_in[2];
  const float* w_lepe = (const float*)d_in[3];
  const float* b_lepe = (const float*)d_in[4];
  const float* w_out  = (const float*)d_in[5];
  const float* b_out  = (const float*)d_in[6];
  float* out = (float*)d_out;
  float* ws  = (float*)d_ws;

  float* qkv  = ws;                        // 384*13824
  float* go   = qkv + (size_t)384 * S;     // 128*13824
  float* qr   = go + (size_t)128 * S;      // 64*128
  float* kr   = qr + 8192;                 // 64*128
  int*   idxb = (int*)(kr + 8192);         // 64*4

  proj_kernel<<<864, 256, 0, stream>>>(x, w_qkv, b_qkv, qkv, 384);
  rmean_kernel<<<64, 256, 0, stream>>>(qkv, qr, kr);
  route_kernel<<<64, 64, 0, stream>>>(qr, kr, idxb);
  attn_kernel<<<dim3(64, 8), 512, 0, stream>>>(qkv, idxb, go);
  lepe_kernel<<<256, 256, 0, stream>>>(qkv + (size_t)256 * S, w_lepe, b_lepe, go);
  proj_kernel<<<864, 256, 0, stream>>>(go, w_out, b_out, out, 128);
}